// Round 1
// baseline (1222.393 us; speedup 1.0000x reference)
//
#include <hip/hip_runtime.h>
#include <math.h>

#define DIMC 64
#define KK 4
#define BATCH 16
#define HH 256
#define WW 256
#define HO 127
#define WO 127
#define PIX (HO*WO)          // 16129
#define OUT_MAIN (BATCH*DIMC*PIX)   // 16516096
#define AGGW_ELEMS (BATCH*DIMC*DIMC*25)  // 1638400

// workspace layout (float offsets)
#define WS_AGGW   0
#define WS_POOLED (AGGW_ELEMS)
#define WS_ATT    (WS_POOLED + BATCH*DIMC)
#define WS_AGGB   (WS_ATT + BATCH*KK)

// ---------------- kernel 1: global average pool ----------------
__global__ void pool_kernel(const float* __restrict__ x, float* __restrict__ ws) {
    int bc = blockIdx.x;  // 0..1023 = b*64+c
    const float4* p4 = (const float4*)(x + (size_t)bc * (HH*WW));
    int tid = threadIdx.x;
    float s = 0.f;
    for (int k = tid; k < (HH*WW/4); k += 256) {
        float4 v = p4[k];
        s += v.x + v.y + v.z + v.w;
    }
    for (int off = 32; off > 0; off >>= 1)
        s += __shfl_down(s, off, 64);
    __shared__ float red[4];
    int lane = tid & 63, wv = tid >> 6;
    if (lane == 0) red[wv] = s;
    __syncthreads();
    if (tid == 0) {
        float t = red[0] + red[1] + red[2] + red[3];
        ws[WS_POOLED + bc] = t * (1.0f / (HH*WW));
    }
}

// ---------------- kernel 2: attention + agg_b ----------------
__global__ void att_kernel(const float* __restrict__ fc1_w, const float* __restrict__ fc1_b,
                           const float* __restrict__ fc2_w, const float* __restrict__ fc2_b,
                           const float* __restrict__ bias, float* __restrict__ ws) {
    __shared__ float satt[BATCH*KK];
    int tid = threadIdx.x;
    if (tid < BATCH) {
        int b = tid;
        const float* pooled = ws + WS_POOLED + b*DIMC;
        float a[KK];
        #pragma unroll
        for (int j = 0; j < KK; ++j) {
            float s = fc1_b[j];
            for (int i = 0; i < DIMC; ++i) s += pooled[i] * fc1_w[j*DIMC + i];
            a[j] = fmaxf(s, 0.f);
        }
        float l[KK]; float m = -1e30f;
        #pragma unroll
        for (int j = 0; j < KK; ++j) {
            float s = fc2_b[j];
            #pragma unroll
            for (int k = 0; k < KK; ++k) s += a[k] * fc2_w[j*KK + k];
            l[j] = s; m = fmaxf(m, s);
        }
        float e[KK]; float Z = 0.f;
        #pragma unroll
        for (int j = 0; j < KK; ++j) { e[j] = expf(l[j] - m); Z += e[j]; }
        float invZ = 1.f / Z;
        #pragma unroll
        for (int j = 0; j < KK; ++j) {
            float av = e[j] * invZ;
            satt[b*KK + j] = av;
            ws[WS_ATT + b*KK + j] = av;
        }
    }
    __syncthreads();
    for (int idx = tid; idx < BATCH*DIMC; idx += blockDim.x) {
        int b = idx / DIMC, o = idx % DIMC;
        float s = 0.f;
        #pragma unroll
        for (int k = 0; k < KK; ++k) s += satt[b*KK + k] * bias[k*DIMC + o];
        ws[WS_AGGB + idx] = s;
    }
}

// ---------------- kernel 3: mix weight bank; write w_ret + agg_w ----------------
// thread index v ordered exactly as w_ret flat: ((b*64+o)*25 + t)*64 + i
__global__ void agg_kernel(const float* __restrict__ weight, const float* __restrict__ att,
                           float* __restrict__ aggw, float* __restrict__ wret) {
    int v = blockIdx.x * 256 + threadIdx.x;   // 0..1638399
    int i = v & 63;
    int t = (v >> 6) % 25;
    int o = (v / 1600) & 63;
    int b = v / 102400;
    float s = 0.f;
    #pragma unroll
    for (int k = 0; k < KK; ++k)
        s += att[b*KK + k] * weight[((k*DIMC + o)*DIMC + i)*25 + t];
    wret[v] = s;                                  // (b*64+o, t, i) — coalesced
    aggw[((b*DIMC + i)*25 + t)*64 + o] = s;       // [b][cin][tap][cout]
}

// ---------------- kernel 4: per-sample 5x5 stride-2 conv ----------------
// block: 32x8 output pixels x 16 couts; thread: 2x2 pixels x 4 couts
__global__ __launch_bounds__(256) void conv_kernel(const float* __restrict__ x,
                                                   const float* __restrict__ ws,
                                                   float* __restrict__ out) {
    __shared__ float lin[19*68];
    __shared__ float lw[25*16];
    int tile   = blockIdx.x;          // 0..63
    int cb     = blockIdx.y;          // 0..3
    int b      = blockIdx.z;          // 0..15
    int tile_x = tile & 3, tile_y = tile >> 2;
    int tid = threadIdx.x;
    int sx = tid & 15, sy = (tid >> 4) & 3, cg = tid >> 6;  // cg 0..3
    int co_base = cb * 16;
    int gx0 = tile_x*64 - 1, gy0 = tile_y*16 - 1;
    const float* aggw = ws + WS_AGGW;
    const float* xbase = x + (size_t)b * (DIMC*HH*WW);

    float acc[2][2][4];
    #pragma unroll
    for (int qy = 0; qy < 2; ++qy)
        #pragma unroll
        for (int qx = 0; qx < 2; ++qx)
            #pragma unroll
            for (int j = 0; j < 4; ++j) acc[qy][qx][j] = 0.f;

    for (int ci = 0; ci < DIMC; ++ci) {
        __syncthreads();
        const float* xs = xbase + ci*(HH*WW);
        for (int idx = tid; idx < 19*67; idx += 256) {
            int r = idx / 67;
            int c = idx - r*67;
            int gy = gy0 + r, gx = gx0 + c;
            float vv = 0.f;
            if ((unsigned)gy < (unsigned)HH && (unsigned)gx < (unsigned)WW)
                vv = xs[gy*WW + gx];
            lin[r*68 + c] = vv;
        }
        const float* wsrc = aggw + (size_t)(b*DIMC + ci)*25*64 + co_base;
        if (tid < 400 - 256) { }  // (no-op; staging below covers all)
        for (int idx = tid; idx < 400; idx += 256) {
            int t = idx >> 4, j = idx & 15;
            lw[idx] = wsrc[t*64 + j];
        }
        __syncthreads();

        #pragma unroll
        for (int dy = 0; dy < 5; ++dy) {
            const float* rA = &lin[(4*sy + dy)*68 + 4*sx];
            const float* rB = rA + 2*68;
            float4 a0 = *(const float4*)(rA);
            float4 a1 = *(const float4*)(rA + 4);
            float4 b0 = *(const float4*)(rB);
            float4 b1 = *(const float4*)(rB + 4);
            float ar[8] = {a0.x,a0.y,a0.z,a0.w,a1.x,a1.y,a1.z,a1.w};
            float br[8] = {b0.x,b0.y,b0.z,b0.w,b1.x,b1.y,b1.z,b1.w};
            #pragma unroll
            for (int dx = 0; dx < 5; ++dx) {
                float4 wv = *(const float4*)&lw[(dy*5 + dx)*16 + 4*cg];
                float wj[4] = {wv.x, wv.y, wv.z, wv.w};
                #pragma unroll
                for (int j = 0; j < 4; ++j) {
                    acc[0][0][j] += ar[dx]     * wj[j];
                    acc[0][1][j] += ar[dx + 2] * wj[j];
                    acc[1][0][j] += br[dx]     * wj[j];
                    acc[1][1][j] += br[dx + 2] * wj[j];
                }
            }
        }
    }

    const float* aggb = ws + WS_AGGB + b*DIMC + co_base + 4*cg;
    float bb[4] = {aggb[0], aggb[1], aggb[2], aggb[3]};
    int oy0 = tile_y*8 + 2*sy, ox0 = tile_x*32 + 2*sx;
    #pragma unroll
    for (int qy = 0; qy < 2; ++qy) {
        int oy = oy0 + qy;
        if (oy >= HO) continue;
        #pragma unroll
        for (int qx = 0; qx < 2; ++qx) {
            int ox = ox0 + qx;
            if (ox >= WO) continue;
            #pragma unroll
            for (int j = 0; j < 4; ++j) {
                int co = co_base + 4*cg + j;
                out[(size_t)(b*DIMC + co)*PIX + oy*WO + ox] = acc[qy][qx][j] + bb[j];
            }
        }
    }
}

extern "C" void kernel_launch(void* const* d_in, const int* in_sizes, int n_in,
                              void* d_out, int out_size, void* d_ws, size_t ws_size,
                              hipStream_t stream) {
    const float* x      = (const float*)d_in[0];
    const float* fc1_w  = (const float*)d_in[1];
    const float* fc1_b  = (const float*)d_in[2];
    const float* fc2_w  = (const float*)d_in[3];
    const float* fc2_b  = (const float*)d_in[4];
    const float* weight = (const float*)d_in[5];
    const float* bias   = (const float*)d_in[6];
    float* out = (float*)d_out;
    float* ws  = (float*)d_ws;

    pool_kernel<<<BATCH*DIMC, 256, 0, stream>>>(x, ws);
    att_kernel<<<1, 256, 0, stream>>>(fc1_w, fc1_b, fc2_w, fc2_b, bias, ws);
    agg_kernel<<<AGGW_ELEMS/256, 256, 0, stream>>>(weight, ws + WS_ATT,
                                                   ws + WS_AGGW, out + OUT_MAIN);
    conv_kernel<<<dim3(64, 4, 16), 256, 0, stream>>>(x, ws, out);
}

// Round 2
// 880.572 us; speedup vs baseline: 1.3882x; 1.3882x over previous
//
#include <hip/hip_runtime.h>
#include <math.h>

#define DIMC 64
#define KK 4
#define BATCH 16
#define HH 256
#define WW 256
#define HO 127
#define WO 127
#define PIX (HO*WO)                  // 16129
#define OUT_MAIN (BATCH*DIMC*PIX)    // 16516096

typedef __bf16 bf16x4 __attribute__((ext_vector_type(4)));
typedef __bf16 bf16x8 __attribute__((ext_vector_type(8)));
typedef float floatx16 __attribute__((ext_vector_type(16)));

// workspace float offsets
#define WS_A2F    0                          // bf16 agg_w: 1,638,400 bf16 = 819,200 floats
#define WS_POOLED 819200
#define WS_ATT    (WS_POOLED + BATCH*DIMC)   // 820224
#define WS_AGGB   (WS_ATT + BATCH*KK)        // 820288

// ---------------- kernel 1: global average pool (partial sums + atomic) ----------------
__global__ void pool_kernel(const float* __restrict__ x, float* __restrict__ pooled) {
    int plane = blockIdx.x >> 1, half = blockIdx.x & 1;
    const float4* p = (const float4*)(x + (size_t)plane * (HH*WW)) + half * 8192;
    float s = 0.f;
    for (int k = threadIdx.x; k < 8192; k += 256) {
        float4 v = p[k];
        s += (v.x + v.y) + (v.z + v.w);
    }
    for (int off = 32; off > 0; off >>= 1) s += __shfl_down(s, off, 64);
    __shared__ float red[4];
    if ((threadIdx.x & 63) == 0) red[threadIdx.x >> 6] = s;
    __syncthreads();
    if (threadIdx.x == 0) atomicAdd(&pooled[plane], red[0] + red[1] + red[2] + red[3]);
}

// ---------------- kernel 2: attention + agg_b ----------------
__global__ void att_kernel(const float* __restrict__ fc1_w, const float* __restrict__ fc1_b,
                           const float* __restrict__ fc2_w, const float* __restrict__ fc2_b,
                           const float* __restrict__ bias, float* __restrict__ ws) {
    __shared__ float satt[BATCH*KK];
    int tid = threadIdx.x;
    if (tid < BATCH) {
        int b = tid;
        const float* pooled = ws + WS_POOLED + b*DIMC;
        float a[KK];
        #pragma unroll
        for (int j = 0; j < KK; ++j) {
            float s = fc1_b[j];
            for (int i = 0; i < DIMC; ++i) s += pooled[i] * (1.f/65536.f) * fc1_w[j*DIMC + i];
            a[j] = fmaxf(s, 0.f);
        }
        float l[KK]; float m = -1e30f;
        #pragma unroll
        for (int j = 0; j < KK; ++j) {
            float s = fc2_b[j];
            #pragma unroll
            for (int k = 0; k < KK; ++k) s += a[k] * fc2_w[j*KK + k];
            l[j] = s; m = fmaxf(m, s);
        }
        float e[KK]; float Z = 0.f;
        #pragma unroll
        for (int j = 0; j < KK; ++j) { e[j] = expf(l[j] - m); Z += e[j]; }
        float invZ = 1.f / Z;
        #pragma unroll
        for (int j = 0; j < KK; ++j) {
            float av = e[j] * invZ;
            satt[b*KK + j] = av;
            ws[WS_ATT + b*KK + j] = av;
        }
    }
    __syncthreads();
    for (int idx = tid; idx < BATCH*DIMC; idx += blockDim.x) {
        int b = idx / DIMC, o = idx % DIMC;
        float s = 0.f;
        #pragma unroll
        for (int k = 0; k < KK; ++k) s += satt[b*KK + k] * bias[k*DIMC + o];
        ws[WS_AGGB + idx] = s;
    }
}

// ---------------- kernel 3: mix weight bank -> w_ret (fp32) + A2 (bf16, MFMA-A layout) ----------------
// v ordered exactly as w_ret flat: ((b*64+o)*25 + t)*64 + i
__global__ void agg_kernel(const float* __restrict__ weight, const float* __restrict__ att,
                           __bf16* __restrict__ a2, float* __restrict__ wret) {
    int v = blockIdx.x * 256 + threadIdx.x;   // 0..1638399
    int i = v & 63;                            // ci
    int t = (v >> 6) % 25;                     // tap
    int o = (v / 1600) & 63;                   // cout
    int b = v / 102400;
    float s = 0.f;
    #pragma unroll
    for (int k = 0; k < KK; ++k)
        s += att[b*KK + k] * weight[((k*DIMC + o)*DIMC + i)*25 + t];
    wret[v] = s;                               // coalesced fp32
    // A2 layout: [b][chunk=i>>4][tap][cout][ci&15]
    a2[(((b*4 + (i >> 4))*25 + t)*64 + o)*16 + (i & 15)] = (__bf16)s;
}

// ---------------- kernel 4: MFMA conv (tap-decomposed implicit GEMM) ----------------
// block: b x (4 output rows) x (32 cols) x 64 couts. 4 waves: (m-half, row-pair).
// wave: M=32 couts x N=64 pixels (2 n-tiles = 2 rows), acc 2x16 fp32.
#define IXP 68
#define CIP 20
__global__ __launch_bounds__(256) void conv_kernel(const float* __restrict__ x,
                                                   const __bf16* __restrict__ a2,
                                                   const float* __restrict__ aggb,
                                                   float* __restrict__ out) {
    __shared__ __bf16 lin[11*IXP*CIP];   // 29,920 B
    int ct = blockIdx.x;      // col tile 0..3 (32 cols each)
    int rg = blockIdx.y;      // row group 0..31 (4 rows each)
    int b  = blockIdx.z;
    int tid = threadIdx.x, lane = tid & 63, w = tid >> 6;
    int mh = w & 1;           // cout half
    int rp = w >> 1;          // row pair: rows {2rp, 2rp+1}
    int n = lane & 31, h = lane >> 5;
    floatx16 acc0 = {}, acc1 = {};
    int gx0 = ct*64 - 1;
    int gy0 = rg*8 - 1;
    const float* xb = x + (size_t)b * (DIMC*HH*WW);
    // per-lane constant part of B-frag LDS offset: (ix=2n)*CIP + h*8
    int bconst = 40*n + 8*h;

    for (int c = 0; c < 4; ++c) {
        __syncthreads();
        // stage 16 ci planes x 11 input rows x 67 cols, fp32 -> bf16
        for (int rr = w; rr < 176; rr += 4) {
            int s = rr / 11, iy = rr - s*11;
            int gy = gy0 + iy;
            bool rowok = (unsigned)gy < (unsigned)HH;
            const float* row = xb + (size_t)(c*16 + s)*(HH*WW) + gy*WW;
            int gx = gx0 + lane;
            float v0 = 0.f;
            if (rowok && (unsigned)gx < (unsigned)WW) v0 = row[gx];
            lin[(iy*IXP + lane)*CIP + s] = (__bf16)v0;
            int ix2 = lane + 64;
            if (ix2 < 67) {
                int gx2 = gx0 + ix2;
                float v1 = 0.f;
                if (rowok && (unsigned)gx2 < (unsigned)WW) v1 = row[gx2];
                lin[(iy*IXP + ix2)*CIP + s] = (__bf16)v1;
            }
        }
        __syncthreads();

        // A-frag base for this (b, chunk, m-half, lane)
        const __bf16* ap = a2 + ((size_t)(b*4 + c)*25*64 + (size_t)(mh*32 + n))*16 + h*8;
        #pragma unroll 5
        for (int t = 0; t < 25; ++t) {
            int dy = t / 5, dx = t - dy*5;
            bf16x8 a = *(const bf16x8*)(ap + t*1024);
            {
                int iy = 4*rp + dy;          // row 2rp -> iy = 2*(2rp)+dy
                const __bf16* bp = lin + iy*(IXP*CIP) + dx*CIP + bconst;
                bf16x4 lo = *(const bf16x4*)bp;
                bf16x4 hi = *(const bf16x4*)(bp + 4);
                bf16x8 bb = __builtin_shufflevector(lo, hi, 0,1,2,3,4,5,6,7);
                acc0 = __builtin_amdgcn_mfma_f32_32x32x16_bf16(a, bb, acc0, 0, 0, 0);
            }
            {
                int iy = 4*rp + 2 + dy;      // row 2rp+1
                const __bf16* bp = lin + iy*(IXP*CIP) + dx*CIP + bconst;
                bf16x4 lo = *(const bf16x4*)bp;
                bf16x4 hi = *(const bf16x4*)(bp + 4);
                bf16x8 bb = __builtin_shufflevector(lo, hi, 0,1,2,3,4,5,6,7);
                acc1 = __builtin_amdgcn_mfma_f32_32x32x16_bf16(a, bb, acc1, 0, 0, 0);
            }
        }
    }

    // epilogue: C/D layout col=lane&31, row=(reg&3)+8*(reg>>2)+4*h
    int oxg = ct*32 + n;
    if (oxg < WO) {
        #pragma unroll
        for (int nt = 0; nt < 2; ++nt) {
            int oy = rg*4 + 2*rp + nt;
            if (oy >= HO) continue;
            const floatx16& acc = nt ? acc1 : acc0;
            #pragma unroll
            for (int reg = 0; reg < 16; ++reg) {
                int row = (reg & 3) + 8*(reg >> 2) + 4*h;
                int cout = mh*32 + row;
                float val = acc[reg] + aggb[b*DIMC + cout];
                out[(size_t)(b*DIMC + cout)*PIX + oy*WO + oxg] = val;
            }
        }
    }
}

extern "C" void kernel_launch(void* const* d_in, const int* in_sizes, int n_in,
                              void* d_out, int out_size, void* d_ws, size_t ws_size,
                              hipStream_t stream) {
    const float* x      = (const float*)d_in[0];
    const float* fc1_w  = (const float*)d_in[1];
    const float* fc1_b  = (const float*)d_in[2];
    const float* fc2_w  = (const float*)d_in[3];
    const float* fc2_b  = (const float*)d_in[4];
    const float* weight = (const float*)d_in[5];
    const float* bias   = (const float*)d_in[6];
    float* out = (float*)d_out;
    float* ws  = (float*)d_ws;
    __bf16* a2 = (__bf16*)d_ws;

    hipMemsetAsync(ws + WS_POOLED, 0, BATCH*DIMC*sizeof(float), stream);
    pool_kernel<<<2*BATCH*DIMC, 256, 0, stream>>>(x, ws + WS_POOLED);
    att_kernel<<<1, 256, 0, stream>>>(fc1_w, fc1_b, fc2_w, fc2_b, bias, ws);
    agg_kernel<<<BATCH*DIMC*DIMC*25/256, 256, 0, stream>>>(weight, ws + WS_ATT,
                                                           a2, out + OUT_MAIN);
    conv_kernel<<<dim3(4, 32, BATCH), 256, 0, stream>>>(x, a2, ws + WS_AGGB, out);
}

// Round 4
// 573.337 us; speedup vs baseline: 2.1321x; 1.5359x over previous
//
#include <hip/hip_runtime.h>
#include <math.h>

#define DIMC 64
#define KK 4
#define BATCH 16
#define HH 256
#define WW 256
#define HO 127
#define WO 127
#define PIX (HO*WO)                  // 16129
#define OUT_MAIN (BATCH*DIMC*PIX)    // 16516096

typedef __bf16 bf16x4 __attribute__((ext_vector_type(4)));
typedef __bf16 bf16x8 __attribute__((ext_vector_type(8)));
typedef float floatx16 __attribute__((ext_vector_type(16)));

// ---------- BIG-WS layout (float offsets) ----------
// a2: 1,638,400 bf16 = 819,200 floats
// xb: 16*4*256*256*16 = 67,108,864 bf16 = 33,554,432 floats
#define BG_A2F    0
#define BG_XB     819200
#define BG_POOLED (BG_XB + 33554432)          // 34,373,632
#define BG_ATT    (BG_POOLED + 1024)
#define BG_AGGB   (BG_ATT + 64)
#define BG_END    (BG_AGGB + 1024)            // 34,375,744 floats
#define BG_NEED_BYTES ((size_t)BG_END * 4)    // ~137.5 MB

// ---------- SMALL-WS (fallback, R2) layout ----------
#define SM_A2F    0
#define SM_POOLED 819200
#define SM_ATT    (SM_POOLED + 1024)
#define SM_AGGB   (SM_ATT + 64)

#define IXN 68
#define CIP 20

// ================= shared kernels =================

// attention + agg_b (pooled holds raw sums; /65536 here)
__global__ void att_kernel(const float* __restrict__ fc1_w, const float* __restrict__ fc1_b,
                           const float* __restrict__ fc2_w, const float* __restrict__ fc2_b,
                           const float* __restrict__ bias,
                           const float* __restrict__ pooled_raw,
                           float* __restrict__ att_out, float* __restrict__ aggb_out) {
    __shared__ float satt[BATCH*KK];
    int tid = threadIdx.x;
    if (tid < BATCH) {
        int b = tid;
        const float* pooled = pooled_raw + b*DIMC;
        float a[KK];
        #pragma unroll
        for (int j = 0; j < KK; ++j) {
            float s = fc1_b[j];
            for (int i = 0; i < DIMC; ++i) s += pooled[i] * (1.f/65536.f) * fc1_w[j*DIMC + i];
            a[j] = fmaxf(s, 0.f);
        }
        float l[KK]; float m = -1e30f;
        #pragma unroll
        for (int j = 0; j < KK; ++j) {
            float s = fc2_b[j];
            #pragma unroll
            for (int k = 0; k < KK; ++k) s += a[k] * fc2_w[j*KK + k];
            l[j] = s; m = fmaxf(m, s);
        }
        float e[KK]; float Z = 0.f;
        #pragma unroll
        for (int j = 0; j < KK; ++j) { e[j] = expf(l[j] - m); Z += e[j]; }
        float invZ = 1.f / Z;
        #pragma unroll
        for (int j = 0; j < KK; ++j) {
            float av = e[j] * invZ;
            satt[b*KK + j] = av;
            att_out[b*KK + j] = av;
        }
    }
    __syncthreads();
    for (int idx = tid; idx < BATCH*DIMC; idx += blockDim.x) {
        int b = idx / DIMC, o = idx % DIMC;
        float s = 0.f;
        #pragma unroll
        for (int k = 0; k < KK; ++k) s += satt[b*KK + k] * bias[k*DIMC + o];
        aggb_out[idx] = s;
    }
}

// mix weight bank -> w_ret (fp32) + a2 (bf16 MFMA-A layout)
__global__ void agg_kernel(const float* __restrict__ weight, const float* __restrict__ att,
                           __bf16* __restrict__ a2, float* __restrict__ wret) {
    int v = blockIdx.x * 256 + threadIdx.x;   // 0..1638399
    int i = v & 63;                            // ci
    int t = (v >> 6) % 25;                     // tap
    int o = (v / 1600) & 63;                   // cout
    int b = v / 102400;
    float s = 0.f;
    #pragma unroll
    for (int k = 0; k < KK; ++k)
        s += att[b*KK + k] * weight[((k*DIMC + o)*DIMC + i)*25 + t];
    wret[v] = s;
    a2[(((b*4 + (i >> 4))*25 + t)*64 + o)*16 + (i & 15)] = (__bf16)s;
}

// ================= BIG-WS fast path =================

// fused pool + fp32->bf16 swizzle: xb layout [b][chunk][y][x][ci16]
__global__ __launch_bounds__(256) void pool_cvt_kernel(const float* __restrict__ x,
                                                       __bf16* __restrict__ xb,
                                                       float* __restrict__ pooled) {
    int y = blockIdx.x, ch = blockIdx.y, b = blockIdx.z;
    int tid = threadIdx.x;
    const float* src = x + (((size_t)(b*DIMC + ch*16))*HH + y)*WW + tid;
    float v[16];
    #pragma unroll
    for (int s = 0; s < 16; ++s) v[s] = src[(size_t)s*HH*WW];
    bf16x8 lo, hi;
    #pragma unroll
    for (int j = 0; j < 8; ++j) { lo[j] = (__bf16)v[j]; hi[j] = (__bf16)v[j+8]; }
    __bf16* dst = xb + ((((size_t)(b*4 + ch))*HH + y)*WW + tid)*16;
    *(bf16x8*)dst = lo;          // byte addr multiple of 32 - aligned
    *(bf16x8*)(dst + 8) = hi;
    #pragma unroll
    for (int s = 0; s < 16; ++s) {
        float t = v[s];
        for (int off = 32; off > 0; off >>= 1) t += __shfl_down(t, off, 64);
        v[s] = t;
    }
    __shared__ float part[4][16];
    int lane = tid & 63, w = tid >> 6;
    if (lane == 0) {
        #pragma unroll
        for (int s = 0; s < 16; ++s) part[w][s] = v[s];
    }
    __syncthreads();
    if (tid < 16) {
        float p = part[0][tid] + part[1][tid] + part[2][tid] + part[3][tid];
        atomicAdd(&pooled[b*DIMC + ch*16 + tid], p);
    }
}

// MFMA conv, staging from pre-converted bf16 xb.
// block: 128 thr = 2 waves; tile = 4 out rows x 32 cols x 64 couts.
// wave rp handles rows {2rp,2rp+1}, BOTH cout halves (B-frag reused 2x).
__global__ __launch_bounds__(128) void conv_big_kernel(const __bf16* __restrict__ xb,
                                                       const __bf16* __restrict__ a2,
                                                       const float* __restrict__ aggb,
                                                       float* __restrict__ out) {
    __shared__ __bf16 lin[11*IXN*CIP];   // 29,920 B
    int ct = blockIdx.x;      // col tile 0..3
    int rg = blockIdx.y;      // row group 0..31
    int b  = blockIdx.z;
    int tid = threadIdx.x, lane = tid & 63, rp = tid >> 6;
    int n = lane & 31, h = lane >> 5;
    int gx0 = ct*64 - 1, gy0 = rg*8 - 1;
    int bconst = 40*n + 8*h;
    floatx16 acc00 = {}, acc01 = {}, acc10 = {}, acc11 = {};

    for (int c = 0; c < 4; ++c) {
        __syncthreads();
        const __bf16* xsrc = xb + ((size_t)(b*4 + c))*HH*WW*16;
        // 11 rows x 67 cols x 16ci in 16-B pieces: 1474 pieces
        #pragma unroll
        for (int it = 0; it < 12; ++it) {
            int idx = it*128 + tid;
            if (idx < 1474) {
                int r = idx / 134;
                int q = idx - r*134;
                int ix = q >> 1, hh = q & 1;
                int gy = gy0 + r, gx = gx0 + ix;
                bf16x8 vv = {};
                if ((unsigned)gy < (unsigned)HH && (unsigned)gx < (unsigned)WW)
                    vv = *(const bf16x8*)(xsrc + ((size_t)gy*WW + gx)*16 + hh*8);
                // two 8-B LDS stores: byte addr = r*2720 + ix*40 + hh*16 (+8), 8-aligned
                __bf16* dp = lin + (r*IXN + ix)*CIP + hh*8;
                bf16x4 vlo = {vv[0], vv[1], vv[2], vv[3]};
                bf16x4 vhi = {vv[4], vv[5], vv[6], vv[7]};
                *(bf16x4*)dp = vlo;
                *(bf16x4*)(dp + 4) = vhi;
            }
        }
        __syncthreads();

        const __bf16* ap = a2 + ((size_t)(b*4 + c)*25*64 + n)*16 + h*8;
        #pragma unroll 5
        for (int t = 0; t < 25; ++t) {
            int dy = t / 5, dx = t - dy*5;
            bf16x8 a0 = *(const bf16x8*)(ap + t*1024);        // couts 0..31
            bf16x8 a1 = *(const bf16x8*)(ap + t*1024 + 512);  // couts 32..63
            {
                int iy = 4*rp + dy;
                const __bf16* bp = lin + (iy*IXN + dx)*CIP + bconst;
                bf16x4 l0 = *(const bf16x4*)bp;
                bf16x4 h0 = *(const bf16x4*)(bp + 4);
                bf16x8 bb = __builtin_shufflevector(l0, h0, 0,1,2,3,4,5,6,7);
                acc00 = __builtin_amdgcn_mfma_f32_32x32x16_bf16(a0, bb, acc00, 0, 0, 0);
                acc01 = __builtin_amdgcn_mfma_f32_32x32x16_bf16(a1, bb, acc01, 0, 0, 0);
            }
            {
                int iy = 4*rp + 2 + dy;
                const __bf16* bp = lin + (iy*IXN + dx)*CIP + bconst;
                bf16x4 l0 = *(const bf16x4*)bp;
                bf16x4 h0 = *(const bf16x4*)(bp + 4);
                bf16x8 bb = __builtin_shufflevector(l0, h0, 0,1,2,3,4,5,6,7);
                acc10 = __builtin_amdgcn_mfma_f32_32x32x16_bf16(a0, bb, acc10, 0, 0, 0);
                acc11 = __builtin_amdgcn_mfma_f32_32x32x16_bf16(a1, bb, acc11, 0, 0, 0);
            }
        }
    }

    int oxg = ct*32 + n;
    if (oxg < WO) {
        #pragma unroll
        for (int nt = 0; nt < 2; ++nt) {
            int oy = rg*4 + 2*rp + nt;
            if (oy >= HO) continue;
            #pragma unroll
            for (int mh = 0; mh < 2; ++mh) {
                const floatx16& acc = nt ? (mh ? acc11 : acc10) : (mh ? acc01 : acc00);
                #pragma unroll
                for (int reg = 0; reg < 16; ++reg) {
                    int cout = mh*32 + (reg & 3) + 8*(reg >> 2) + 4*h;
                    float val = acc[reg] + aggb[b*DIMC + cout];
                    out[(size_t)(b*DIMC + cout)*PIX + oy*WO + oxg] = val;
                }
            }
        }
    }
}

// ================= SMALL-WS fallback (R2 pipeline) =================

__global__ void pool_kernel(const float* __restrict__ x, float* __restrict__ pooled) {
    int plane = blockIdx.x >> 1, half = blockIdx.x & 1;
    const float4* p = (const float4*)(x + (size_t)plane * (HH*WW)) + half * 8192;
    float s = 0.f;
    for (int k = threadIdx.x; k < 8192; k += 256) {
        float4 v = p[k];
        s += (v.x + v.y) + (v.z + v.w);
    }
    for (int off = 32; off > 0; off >>= 1) s += __shfl_down(s, off, 64);
    __shared__ float red[4];
    if ((threadIdx.x & 63) == 0) red[threadIdx.x >> 6] = s;
    __syncthreads();
    if (threadIdx.x == 0) atomicAdd(&pooled[plane], red[0] + red[1] + red[2] + red[3]);
}

// conv staging directly from fp32 x (R2, known-good)
__global__ __launch_bounds__(256) void conv_small_kernel(const float* __restrict__ x,
                                                         const __bf16* __restrict__ a2,
                                                         const float* __restrict__ aggb,
                                                         float* __restrict__ out) {
    __shared__ __bf16 lin[11*IXN*CIP];
    int ct = blockIdx.x;
    int rg = blockIdx.y;
    int b  = blockIdx.z;
    int tid = threadIdx.x, lane = tid & 63, w = tid >> 6;
    int mh = w & 1;
    int rp = w >> 1;
    int n = lane & 31, h = lane >> 5;
    floatx16 acc0 = {}, acc1 = {};
    int gx0 = ct*64 - 1;
    int gy0 = rg*8 - 1;
    const float* xbse = x + (size_t)b * (DIMC*HH*WW);
    int bconst = 40*n + 8*h;

    for (int c = 0; c < 4; ++c) {
        __syncthreads();
        for (int rr = w; rr < 176; rr += 4) {
            int s = rr / 11, iy = rr - s*11;
            int gy = gy0 + iy;
            bool rowok = (unsigned)gy < (unsigned)HH;
            const float* row = xbse + (size_t)(c*16 + s)*(HH*WW) + gy*WW;
            int gx = gx0 + lane;
            float v0 = 0.f;
            if (rowok && (unsigned)gx < (unsigned)WW) v0 = row[gx];
            lin[(iy*IXN + lane)*CIP + s] = (__bf16)v0;
            int ix2 = lane + 64;
            if (ix2 < 67) {
                int gx2 = gx0 + ix2;
                float v1 = 0.f;
                if (rowok && (unsigned)gx2 < (unsigned)WW) v1 = row[gx2];
                lin[(iy*IXN + ix2)*CIP + s] = (__bf16)v1;
            }
        }
        __syncthreads();

        const __bf16* ap = a2 + ((size_t)(b*4 + c)*25*64 + (size_t)(mh*32 + n))*16 + h*8;
        #pragma unroll 5
        for (int t = 0; t < 25; ++t) {
            int dy = t / 5, dx = t - dy*5;
            bf16x8 a = *(const bf16x8*)(ap + t*1024);
            {
                int iy = 4*rp + dy;
                const __bf16* bp = lin + (iy*IXN + dx)*CIP + bconst;
                bf16x4 lo = *(const bf16x4*)bp;
                bf16x4 hi = *(const bf16x4*)(bp + 4);
                bf16x8 bb = __builtin_shufflevector(lo, hi, 0,1,2,3,4,5,6,7);
                acc0 = __builtin_amdgcn_mfma_f32_32x32x16_bf16(a, bb, acc0, 0, 0, 0);
            }
            {
                int iy = 4*rp + 2 + dy;
                const __bf16* bp = lin + (iy*IXN + dx)*CIP + bconst;
                bf16x4 lo = *(const bf16x4*)bp;
                bf16x4 hi = *(const bf16x4*)(bp + 4);
                bf16x8 bb = __builtin_shufflevector(lo, hi, 0,1,2,3,4,5,6,7);
                acc1 = __builtin_amdgcn_mfma_f32_32x32x16_bf16(a, bb, acc1, 0, 0, 0);
            }
        }
    }

    int oxg = ct*32 + n;
    if (oxg < WO) {
        #pragma unroll
        for (int nt = 0; nt < 2; ++nt) {
            int oy = rg*4 + 2*rp + nt;
            if (oy >= HO) continue;
            const floatx16& acc = nt ? acc1 : acc0;
            #pragma unroll
            for (int reg = 0; reg < 16; ++reg) {
                int row = (reg & 3) + 8*(reg >> 2) + 4*h;
                int cout = mh*32 + row;
                float val = acc[reg] + aggb[b*DIMC + cout];
                out[(size_t)(b*DIMC + cout)*PIX + oy*WO + oxg] = val;
            }
        }
    }
}

extern "C" void kernel_launch(void* const* d_in, const int* in_sizes, int n_in,
                              void* d_out, int out_size, void* d_ws, size_t ws_size,
                              hipStream_t stream) {
    const float* x      = (const float*)d_in[0];
    const float* fc1_w  = (const float*)d_in[1];
    const float* fc1_b  = (const float*)d_in[2];
    const float* fc2_w  = (const float*)d_in[3];
    const float* fc2_b  = (const float*)d_in[4];
    const float* weight = (const float*)d_in[5];
    const float* bias   = (const float*)d_in[6];
    float* out = (float*)d_out;
    float* ws  = (float*)d_ws;

    if (ws_size >= BG_NEED_BYTES) {
        __bf16* a2 = (__bf16*)(ws + BG_A2F);
        __bf16* xb = (__bf16*)(ws + BG_XB);
        hipMemsetAsync(ws + BG_POOLED, 0, 1024*sizeof(float), stream);
        pool_cvt_kernel<<<dim3(HH, 4, BATCH), 256, 0, stream>>>(x, xb, ws + BG_POOLED);
        att_kernel<<<1, 256, 0, stream>>>(fc1_w, fc1_b, fc2_w, fc2_b, bias,
                                          ws + BG_POOLED, ws + BG_ATT, ws + BG_AGGB);
        agg_kernel<<<BATCH*DIMC*DIMC*25/256, 256, 0, stream>>>(weight, ws + BG_ATT,
                                                               a2, out + OUT_MAIN);
        conv_big_kernel<<<dim3(4, 32, BATCH), 128, 0, stream>>>(xb, a2, ws + BG_AGGB, out);
    } else {
        __bf16* a2 = (__bf16*)(ws + SM_A2F);
        hipMemsetAsync(ws + SM_POOLED, 0, 1024*sizeof(float), stream);
        pool_kernel<<<2*BATCH*DIMC, 256, 0, stream>>>(x, ws + SM_POOLED);
        att_kernel<<<1, 256, 0, stream>>>(fc1_w, fc1_b, fc2_w, fc2_b, bias,
                                          ws + SM_POOLED, ws + SM_ATT, ws + SM_AGGB);
        agg_kernel<<<BATCH*DIMC*DIMC*25/256, 256, 0, stream>>>(weight, ws + SM_ATT,
                                                               a2, out + OUT_MAIN);
        conv_small_kernel<<<dim3(4, 32, BATCH), 256, 0, stream>>>(x, a2, ws + SM_AGGB, out);
    }
}